// Round 1
// baseline (2623.521 us; speedup 1.0000x reference)
//
#include <hip/hip_runtime.h>

#define E_DIM 1024
#define HEADS 16
#define HD 64

// ---------------------------------------------------------------------------
// Multiway linear: out[row,n] = (sum_k x[row,k]*W(kind)[n,k] + b(kind)[n])*scale
// kind(row) = ((row % T) < split) ? text(0) : image(1)
// grid = (E/64, R/64, 2). Blocks of the wrong kind for their row-tile exit.
// ---------------------------------------------------------------------------
#define TM 64
#define TN 64
#define TK 16

__global__ __launch_bounds__(256) void mw_linear_kernel(
    const float* __restrict__ x,    // (R, E)
    const float* __restrict__ Wt,   // (E, E)
    const float* __restrict__ bt,   // (E)
    const float* __restrict__ Wi,
    const float* __restrict__ bi,
    float* __restrict__ out,        // (R, E)
    const int* __restrict__ split_ptr,
    float scale, int T_)
{
    const int split = *split_ptr;
    const int kind = blockIdx.z;
    const int m0 = blockIdx.y * TM;
    const int n0 = blockIdx.x * TN;
    const int t0 = m0 % T_;   // T_ is a multiple of TM, tile stays in one batch

    if (kind == 0) { if (t0 >= split) return; }
    else           { if (t0 + TM <= split) return; }

    const float* __restrict__ W    = (kind == 0) ? Wt : Wi;
    const float* __restrict__ bias = (kind == 0) ? bt : bi;

    __shared__ float As[TM][TK + 1];
    __shared__ float Bs[TN][TK + 1];

    const int tid = threadIdx.x;
    const int tx = tid & 15;      // 0..15 col group
    const int ty = tid >> 4;      // 0..15 row group

    float acc[4][4];
    #pragma unroll
    for (int i = 0; i < 4; ++i)
        #pragma unroll
        for (int j = 0; j < 4; ++j) acc[i][j] = 0.f;

    const int lr = tid >> 2;            // 0..63 tile row for loads
    const int lc = (tid & 3) << 2;      // 0,4,8,12

    for (int k0 = 0; k0 < E_DIM; k0 += TK) {
        float4 av = *(const float4*)&x[(size_t)(m0 + lr) * E_DIM + k0 + lc];
        float4 bv = *(const float4*)&W[(size_t)(n0 + lr) * E_DIM + k0 + lc];
        As[lr][lc+0]=av.x; As[lr][lc+1]=av.y; As[lr][lc+2]=av.z; As[lr][lc+3]=av.w;
        Bs[lr][lc+0]=bv.x; Bs[lr][lc+1]=bv.y; Bs[lr][lc+2]=bv.z; Bs[lr][lc+3]=bv.w;
        __syncthreads();

        #pragma unroll
        for (int kk = 0; kk < TK; ++kk) {
            float a[4], bb[4];
            #pragma unroll
            for (int i = 0; i < 4; ++i) a[i] = As[ty*4+i][kk];
            #pragma unroll
            for (int j = 0; j < 4; ++j) bb[j] = Bs[tx*4+j][kk];
            #pragma unroll
            for (int i = 0; i < 4; ++i)
                #pragma unroll
                for (int j = 0; j < 4; ++j)
                    acc[i][j] += a[i] * bb[j];
        }
        __syncthreads();
    }

    const int nbase = n0 + tx*4;
    float4 bv = *(const float4*)&bias[nbase];
    #pragma unroll
    for (int i = 0; i < 4; ++i) {
        int m = m0 + ty*4 + i;
        int t = m % T_;
        int rowKind = (t < split) ? 0 : 1;
        if (rowKind != kind) continue;
        float4 ov;
        ov.x = (acc[i][0] + bv.x) * scale;
        ov.y = (acc[i][1] + bv.y) * scale;
        ov.z = (acc[i][2] + bv.z) * scale;
        ov.w = (acc[i][3] + bv.w) * scale;
        *(float4*)&out[(size_t)m * E_DIM + nbase] = ov;
    }
}

// ---------------------------------------------------------------------------
// Flash attention, fp32. One thread per q row; 256-thread blocks share K/V
// LDS tiles (wave-uniform reads -> LDS broadcast, free).
// grid = (T/256, H, B). outp may alias q: each thread reads only its own row
// (fully, at the start) and writes only its own row (at the end).
// ---------------------------------------------------------------------------
__global__ __launch_bounds__(256, 1) void attn_kernel(
    const float* q, const float* k, const float* v,
    const float* __restrict__ mask, float* outp, int T_)
{
    const int tid = threadIdx.x;
    const int h = blockIdx.y;
    const int b = blockIdx.z;
    const int r = blockIdx.x * 256 + tid;

    __shared__ float Ks[64][64];
    __shared__ float Vs[64][64];

    float qreg[64];
    {
        const float* qrow = &q[((size_t)b * T_ + r) * E_DIM + h * HD];
        #pragma unroll
        for (int d4 = 0; d4 < 16; ++d4) {
            float4 t4 = *(const float4*)&qrow[d4 * 4];
            qreg[d4*4+0] = t4.x; qreg[d4*4+1] = t4.y;
            qreg[d4*4+2] = t4.z; qreg[d4*4+3] = t4.w;
        }
    }
    float o[64];
    #pragma unroll
    for (int d = 0; d < 64; ++d) o[d] = 0.f;
    float mrun = -3.402823466e38f, l = 0.f;

    const float* mrow = &mask[(size_t)r * T_];

    #pragma unroll 1
    for (int s0 = 0; s0 < T_; s0 += 64) {
        __syncthreads();
        #pragma unroll
        for (int rep = 0; rep < 4; ++rep) {
            int row = rep * 16 + (tid >> 4);
            int c = (tid & 15) * 4;
            float4 kv4 = *(const float4*)&k[((size_t)b*T_ + s0 + row)*E_DIM + h*HD + c];
            Ks[row][c+0]=kv4.x; Ks[row][c+1]=kv4.y; Ks[row][c+2]=kv4.z; Ks[row][c+3]=kv4.w;
            float4 vv4 = *(const float4*)&v[((size_t)b*T_ + s0 + row)*E_DIM + h*HD + c];
            Vs[row][c+0]=vv4.x; Vs[row][c+1]=vv4.y; Vs[row][c+2]=vv4.z; Vs[row][c+3]=vv4.w;
        }
        __syncthreads();

        #pragma unroll 1
        for (int sub = 0; sub < 4; ++sub) {
            float sc[16];
            #pragma unroll
            for (int jj = 0; jj < 16; ++jj) {
                int j = sub * 16 + jj;
                float acc = 0.f;
                #pragma unroll
                for (int d4 = 0; d4 < 16; ++d4) {
                    float4 kv4 = *(const float4*)&Ks[j][d4*4];
                    acc += qreg[d4*4+0]*kv4.x + qreg[d4*4+1]*kv4.y
                         + qreg[d4*4+2]*kv4.z + qreg[d4*4+3]*kv4.w;
                }
                sc[jj] = acc + mrow[s0 + sub*16 + jj];
            }
            float mt = sc[0];
            #pragma unroll
            for (int jj = 1; jj < 16; ++jj) mt = fmaxf(mt, sc[jj]);
            float mnew = fmaxf(mrun, mt);
            float alpha = __expf(mrun - mnew);
            l *= alpha;
            #pragma unroll
            for (int d = 0; d < 64; ++d) o[d] *= alpha;
            #pragma unroll
            for (int jj = 0; jj < 16; ++jj) { sc[jj] = __expf(sc[jj] - mnew); l += sc[jj]; }
            mrun = mnew;
            #pragma unroll
            for (int jj = 0; jj < 16; ++jj) {
                int j = sub * 16 + jj;
                float pj = sc[jj];
                #pragma unroll
                for (int d4 = 0; d4 < 16; ++d4) {
                    float4 vv4 = *(const float4*)&Vs[j][d4*4];
                    o[d4*4+0] += pj*vv4.x; o[d4*4+1] += pj*vv4.y;
                    o[d4*4+2] += pj*vv4.z; o[d4*4+3] += pj*vv4.w;
                }
            }
        }
    }

    float inv = 1.0f / l;
    float* orow = &outp[((size_t)b * T_ + r) * E_DIM + h * HD];
    #pragma unroll
    for (int d4 = 0; d4 < 16; ++d4) {
        float4 t4;
        t4.x = o[d4*4+0]*inv; t4.y = o[d4*4+1]*inv;
        t4.z = o[d4*4+2]*inv; t4.w = o[d4*4+3]*inv;
        *(float4*)&orow[d4*4] = t4;
    }
}

// ---------------------------------------------------------------------------
// Multiway LayerNorm over rows of (R, 1024). One block (256 thr) per row.
// ---------------------------------------------------------------------------
__global__ __launch_bounds__(256) void mw_ln_kernel(
    const float* __restrict__ x,
    const float* __restrict__ gt, const float* __restrict__ bt,
    const float* __restrict__ gi, const float* __restrict__ bi,
    float* __restrict__ out,
    const int* __restrict__ split_ptr, int T_)
{
    const int split = *split_ptr;
    const int row = blockIdx.x;
    const int t = row % T_;
    const float* __restrict__ g  = (t < split) ? gt : bt == bt ? gi : gi; // placate
    g = (t < split) ? gt : gi;
    const float* __restrict__ bb = (t < split) ? bt : bi;

    const int tid = threadIdx.x;
    const int lane = tid & 63;
    const int wid = tid >> 6;

    __shared__ float red[8];

    float4 xv = *(const float4*)&x[(size_t)row * E_DIM + tid * 4];
    float s = xv.x + xv.y + xv.z + xv.w;
    #pragma unroll
    for (int off = 1; off < 64; off <<= 1) s += __shfl_xor(s, off, 64);
    if (lane == 0) red[wid] = s;
    __syncthreads();
    float mu = (red[0] + red[1] + red[2] + red[3]) * (1.0f / E_DIM);

    float4 d;
    d.x = xv.x - mu; d.y = xv.y - mu; d.z = xv.z - mu; d.w = xv.w - mu;
    float s2 = d.x*d.x + d.y*d.y + d.z*d.z + d.w*d.w;
    #pragma unroll
    for (int off = 1; off < 64; off <<= 1) s2 += __shfl_xor(s2, off, 64);
    if (lane == 0) red[4 + wid] = s2;
    __syncthreads();
    float var = (red[4] + red[5] + red[6] + red[7]) * (1.0f / E_DIM);
    float rstd = rsqrtf(var + 1e-5f);

    float4 gv = *(const float4*)&g[tid * 4];
    float4 bv = *(const float4*)&bb[tid * 4];
    float4 ov;
    ov.x = d.x * rstd * gv.x + bv.x;
    ov.y = d.y * rstd * gv.y + bv.y;
    ov.z = d.z * rstd * gv.z + bv.z;
    ov.w = d.w * rstd * gv.w + bv.w;
    *(float4*)&out[(size_t)row * E_DIM + tid * 4] = ov;
}

// ---------------------------------------------------------------------------
extern "C" void kernel_launch(void* const* d_in, const int* in_sizes, int n_in,
                              void* d_out, int out_size, void* d_ws, size_t ws_size,
                              hipStream_t stream) {
    const float* query = (const float*)d_in[0];
    const float* key   = (const float*)d_in[1];
    const float* value = (const float*)d_in[2];
    const float* mask  = (const float*)d_in[3];
    const float* Wq_t = (const float*)d_in[4];  const float* bq_t = (const float*)d_in[5];
    const float* Wq_i = (const float*)d_in[6];  const float* bq_i = (const float*)d_in[7];
    const float* Wk_t = (const float*)d_in[8];  const float* bk_t = (const float*)d_in[9];
    const float* Wk_i = (const float*)d_in[10]; const float* bk_i = (const float*)d_in[11];
    const float* Wv_t = (const float*)d_in[12]; const float* bv_t = (const float*)d_in[13];
    const float* Wv_i = (const float*)d_in[14]; const float* bv_i = (const float*)d_in[15];
    const float* Wo_t = (const float*)d_in[16]; const float* bo_t = (const float*)d_in[17];
    const float* Wo_i = (const float*)d_in[18]; const float* bo_i = (const float*)d_in[19];
    const float* ln_g_t = (const float*)d_in[20]; const float* ln_b_t = (const float*)d_in[21];
    const float* ln_g_i = (const float*)d_in[22]; const float* ln_b_i = (const float*)d_in[23];
    const int* split = (const int*)d_in[24];

    float* out = (float*)d_out;

    const int BT = in_sizes[0] / E_DIM;   // B*T = 8192
    const int T_ = 1024;                  // per reference setup
    const int B  = BT / T_;

    float* ws = (float*)d_ws;
    const size_t buf = (size_t)BT * E_DIM;   // 8M floats = 32MB
    float* q_ws = ws;
    float* k_ws = ws + buf;
    float* v_ws = ws + 2 * buf;

    dim3 blk(256);
    dim3 ggrid(E_DIM / TN, BT / TM, 2);

    const float scaling = 0.125f;  // HD^-0.5

    mw_linear_kernel<<<ggrid, blk, 0, stream>>>(query, Wq_t, bq_t, Wq_i, bq_i, q_ws, split, scaling, T_);
    mw_linear_kernel<<<ggrid, blk, 0, stream>>>(key,   Wk_t, bk_t, Wk_i, bk_i, k_ws, split, 1.0f, T_);
    mw_linear_kernel<<<ggrid, blk, 0, stream>>>(value, Wv_t, bv_t, Wv_i, bv_i, v_ws, split, 1.0f, T_);

    dim3 agrid(T_ / 256, HEADS, B);
    attn_kernel<<<agrid, blk, 0, stream>>>(q_ws, k_ws, v_ws, mask, q_ws, T_);

    mw_ln_kernel<<<dim3(BT), blk, 0, stream>>>(q_ws, ln_g_t, ln_b_t, ln_g_i, ln_b_i, k_ws, split, T_);

    mw_linear_kernel<<<ggrid, blk, 0, stream>>>(k_ws, Wo_t, bo_t, Wo_i, bo_i, out, split, 1.0f, T_);
}

// Round 2
// 1551.872 us; speedup vs baseline: 1.6906x; 1.6906x over previous
//
#include <hip/hip_runtime.h>

#define E_DIM 1024
#define HEADS 16
#define HD 64

typedef __attribute__((ext_vector_type(8))) short bf16x8;
typedef __attribute__((ext_vector_type(4))) float floatx4;

// round-half-up fp32 -> bf16, pack two into one dword (lo = a, hi = b)
__device__ inline unsigned int pack2bf(float a, float b) {
    unsigned int ua = __builtin_bit_cast(unsigned int, a);
    unsigned int ub = __builtin_bit_cast(unsigned int, b);
    ua = (ua + 0x8000u) >> 16;
    ub = (ub + 0x8000u) & 0xFFFF0000u;
    return ua | ub;
}

// ---------------------------------------------------------------------------
// Multiway linear, bf16 MFMA: out[m,n] = (sum_k x[m,k]*W(kind)[n,k] + b[n])*scale
// 128x128 block tile, 256 threads = 4 waves (2x2 of 64x64), BK=32,
// fp32 sources converted to bf16 during LDS staging.
// grid = (E/128, R/128, 2 kinds); wrong-kind tiles exit; straddle tiles
// computed by both kinds with per-row write masks.
// ---------------------------------------------------------------------------
#define GM 128
#define GN 128
#define GK 32
#define LDK 40   // padded LDS row stride in elements (80B = 5*16B, keeps b128 alignment)

__global__ __launch_bounds__(256) void mw_linear_mfma(
    const float* __restrict__ x,    // (R, E)
    const float* __restrict__ Wt,   // (E, E) row-major, C = x @ W^T
    const float* __restrict__ bt,
    const float* __restrict__ Wi,
    const float* __restrict__ bi,
    float* __restrict__ out,        // (R, E)
    const int* __restrict__ split_ptr,
    float scale, int T_)
{
    const int split = *split_ptr;
    const int kind = blockIdx.z;
    const int m0 = blockIdx.y * GM;
    const int n0 = blockIdx.x * GN;
    const int t0 = m0 % T_;   // T_ multiple of GM -> tile within one batch

    if (kind == 0) { if (t0 >= split) return; }
    else           { if (t0 + GM <= split) return; }

    const float* __restrict__ W    = (kind == 0) ? Wt : Wi;
    const float* __restrict__ bias = (kind == 0) ? bt : bi;

    __shared__ __align__(16) unsigned short As[GM * LDK];
    __shared__ __align__(16) unsigned short Bs[GN * LDK];

    const int tid  = threadIdx.x;
    const int lane = tid & 63;
    const int wv   = tid >> 6;          // wave 0..3
    const int rw   = (wv >> 1) * 64;    // wave's row offset in tile
    const int cw   = (wv & 1) * 64;     // wave's col offset in tile

    // staging mapping: iter i: row = (tid>>3) + i*32, col = (tid&7)*4 (fp32 elems)
    const int srow = tid >> 3;
    const int scol = (tid & 7) * 4;

    floatx4 acc[4][4];
    #pragma unroll
    for (int i = 0; i < 4; ++i)
        #pragma unroll
        for (int j = 0; j < 4; ++j)
            acc[i][j] = (floatx4){0.f, 0.f, 0.f, 0.f};

    const int am = lane & 15;   // fragment row/col within 16
    const int aq = lane >> 4;   // quad 0..3 -> k offset aq*8

    for (int k0 = 0; k0 < E_DIM; k0 += GK) {
        #pragma unroll
        for (int i = 0; i < 4; ++i) {
            int r = srow + i * 32;
            float4 a4 = *(const float4*)&x[(size_t)(m0 + r) * E_DIM + k0 + scol];
            float4 b4 = *(const float4*)&W[(size_t)(n0 + r) * E_DIM + k0 + scol];
            *(unsigned int*)&As[r * LDK + scol]     = pack2bf(a4.x, a4.y);
            *(unsigned int*)&As[r * LDK + scol + 2] = pack2bf(a4.z, a4.w);
            *(unsigned int*)&Bs[r * LDK + scol]     = pack2bf(b4.x, b4.y);
            *(unsigned int*)&Bs[r * LDK + scol + 2] = pack2bf(b4.z, b4.w);
        }
        __syncthreads();

        bf16x8 af[4], bfv[4];
        #pragma unroll
        for (int i = 0; i < 4; ++i)
            af[i] = *(const bf16x8*)&As[(rw + i * 16 + am) * LDK + aq * 8];
        #pragma unroll
        for (int j = 0; j < 4; ++j)
            bfv[j] = *(const bf16x8*)&Bs[(cw + j * 16 + am) * LDK + aq * 8];

        #pragma unroll
        for (int i = 0; i < 4; ++i)
            #pragma unroll
            for (int j = 0; j < 4; ++j)
                acc[i][j] = __builtin_amdgcn_mfma_f32_16x16x32_bf16(af[i], bfv[j], acc[i][j], 0, 0, 0);
        __syncthreads();
    }

    // Epilogue. C/D layout: col = lane&15, row = (lane>>4)*4 + reg  [m89]
    const int cq = lane >> 4;
    const int cm = lane & 15;
    #pragma unroll
    for (int j = 0; j < 4; ++j) {
        int n = n0 + cw + j * 16 + cm;
        float bv = bias[n];
        #pragma unroll
        for (int i = 0; i < 4; ++i) {
            int mbase = m0 + rw + i * 16 + cq * 4;
            #pragma unroll
            for (int r = 0; r < 4; ++r) {
                int m = mbase + r;
                int t = m % T_;
                if (((t < split) ? 0 : 1) != kind) continue;
                out[(size_t)m * E_DIM + n] = (acc[i][j][r] + bv) * scale;
            }
        }
    }
}

// ---------------------------------------------------------------------------
// Flash attention, fp32 (unchanged from round 1). One thread per q row.
// ---------------------------------------------------------------------------
__global__ __launch_bounds__(256, 1) void attn_kernel(
    const float* q, const float* k, const float* v,
    const float* __restrict__ mask, float* outp, int T_)
{
    const int tid = threadIdx.x;
    const int h = blockIdx.y;
    const int b = blockIdx.z;
    const int r = blockIdx.x * 256 + tid;

    __shared__ float Ks[64][64];
    __shared__ float Vs[64][64];

    float qreg[64];
    {
        const float* qrow = &q[((size_t)b * T_ + r) * E_DIM + h * HD];
        #pragma unroll
        for (int d4 = 0; d4 < 16; ++d4) {
            float4 t4 = *(const float4*)&qrow[d4 * 4];
            qreg[d4*4+0] = t4.x; qreg[d4*4+1] = t4.y;
            qreg[d4*4+2] = t4.z; qreg[d4*4+3] = t4.w;
        }
    }
    float o[64];
    #pragma unroll
    for (int d = 0; d < 64; ++d) o[d] = 0.f;
    float mrun = -3.402823466e38f, l = 0.f;

    const float* mrow = &mask[(size_t)r * T_];

    #pragma unroll 1
    for (int s0 = 0; s0 < T_; s0 += 64) {
        __syncthreads();
        #pragma unroll
        for (int rep = 0; rep < 4; ++rep) {
            int row = rep * 16 + (tid >> 4);
            int c = (tid & 15) * 4;
            float4 kv4 = *(const float4*)&k[((size_t)b*T_ + s0 + row)*E_DIM + h*HD + c];
            Ks[row][c+0]=kv4.x; Ks[row][c+1]=kv4.y; Ks[row][c+2]=kv4.z; Ks[row][c+3]=kv4.w;
            float4 vv4 = *(const float4*)&v[((size_t)b*T_ + s0 + row)*E_DIM + h*HD + c];
            Vs[row][c+0]=vv4.x; Vs[row][c+1]=vv4.y; Vs[row][c+2]=vv4.z; Vs[row][c+3]=vv4.w;
        }
        __syncthreads();

        #pragma unroll 1
        for (int sub = 0; sub < 4; ++sub) {
            float sc[16];
            #pragma unroll
            for (int jj = 0; jj < 16; ++jj) {
                int j = sub * 16 + jj;
                float acc = 0.f;
                #pragma unroll
                for (int d4 = 0; d4 < 16; ++d4) {
                    float4 kv4 = *(const float4*)&Ks[j][d4*4];
                    acc += qreg[d4*4+0]*kv4.x + qreg[d4*4+1]*kv4.y
                         + qreg[d4*4+2]*kv4.z + qreg[d4*4+3]*kv4.w;
                }
                sc[jj] = acc + mrow[s0 + sub*16 + jj];
            }
            float mt = sc[0];
            #pragma unroll
            for (int jj = 1; jj < 16; ++jj) mt = fmaxf(mt, sc[jj]);
            float mnew = fmaxf(mrun, mt);
            float alpha = __expf(mrun - mnew);
            l *= alpha;
            #pragma unroll
            for (int d = 0; d < 64; ++d) o[d] *= alpha;
            #pragma unroll
            for (int jj = 0; jj < 16; ++jj) { sc[jj] = __expf(sc[jj] - mnew); l += sc[jj]; }
            mrun = mnew;
            #pragma unroll
            for (int jj = 0; jj < 16; ++jj) {
                int j = sub * 16 + jj;
                float pj = sc[jj];
                #pragma unroll
                for (int d4 = 0; d4 < 16; ++d4) {
                    float4 vv4 = *(const float4*)&Vs[j][d4*4];
                    o[d4*4+0] += pj*vv4.x; o[d4*4+1] += pj*vv4.y;
                    o[d4*4+2] += pj*vv4.z; o[d4*4+3] += pj*vv4.w;
                }
            }
        }
    }

    float inv = 1.0f / l;
    float* orow = &outp[((size_t)b * T_ + r) * E_DIM + h * HD];
    #pragma unroll
    for (int d4 = 0; d4 < 16; ++d4) {
        float4 t4;
        t4.x = o[d4*4+0]*inv; t4.y = o[d4*4+1]*inv;
        t4.z = o[d4*4+2]*inv; t4.w = o[d4*4+3]*inv;
        *(float4*)&orow[d4*4] = t4;
    }
}

// ---------------------------------------------------------------------------
// Multiway LayerNorm over rows of (R, 1024). One block (256 thr) per row.
// ---------------------------------------------------------------------------
__global__ __launch_bounds__(256) void mw_ln_kernel(
    const float* __restrict__ x,
    const float* __restrict__ gt, const float* __restrict__ bt,
    const float* __restrict__ gi, const float* __restrict__ bi,
    float* __restrict__ out,
    const int* __restrict__ split_ptr, int T_)
{
    const int split = *split_ptr;
    const int row = blockIdx.x;
    const int t = row % T_;
    const float* __restrict__ g  = (t < split) ? gt : gi;
    const float* __restrict__ bb = (t < split) ? bt : bi;

    const int tid = threadIdx.x;
    const int lane = tid & 63;
    const int wid = tid >> 6;

    __shared__ float red[8];

    float4 xv = *(const float4*)&x[(size_t)row * E_DIM + tid * 4];
    float s = xv.x + xv.y + xv.z + xv.w;
    #pragma unroll
    for (int off = 1; off < 64; off <<= 1) s += __shfl_xor(s, off, 64);
    if (lane == 0) red[wid] = s;
    __syncthreads();
    float mu = (red[0] + red[1] + red[2] + red[3]) * (1.0f / E_DIM);

    float4 d;
    d.x = xv.x - mu; d.y = xv.y - mu; d.z = xv.z - mu; d.w = xv.w - mu;
    float s2 = d.x*d.x + d.y*d.y + d.z*d.z + d.w*d.w;
    #pragma unroll
    for (int off = 1; off < 64; off <<= 1) s2 += __shfl_xor(s2, off, 64);
    if (lane == 0) red[4 + wid] = s2;
    __syncthreads();
    float var = (red[4] + red[5] + red[6] + red[7]) * (1.0f / E_DIM);
    float rstd = rsqrtf(var + 1e-5f);

    float4 gv = *(const float4*)&g[tid * 4];
    float4 bv = *(const float4*)&bb[tid * 4];
    float4 ov;
    ov.x = d.x * rstd * gv.x + bv.x;
    ov.y = d.y * rstd * gv.y + bv.y;
    ov.z = d.z * rstd * gv.z + bv.z;
    ov.w = d.w * rstd * gv.w + bv.w;
    *(float4*)&out[(size_t)row * E_DIM + tid * 4] = ov;
}

// ---------------------------------------------------------------------------
extern "C" void kernel_launch(void* const* d_in, const int* in_sizes, int n_in,
                              void* d_out, int out_size, void* d_ws, size_t ws_size,
                              hipStream_t stream) {
    const float* query = (const float*)d_in[0];
    const float* key   = (const float*)d_in[1];
    const float* value = (const float*)d_in[2];
    const float* mask  = (const float*)d_in[3];
    const float* Wq_t = (const float*)d_in[4];  const float* bq_t = (const float*)d_in[5];
    const float* Wq_i = (const float*)d_in[6];  const float* bq_i = (const float*)d_in[7];
    const float* Wk_t = (const float*)d_in[8];  const float* bk_t = (const float*)d_in[9];
    const float* Wk_i = (const float*)d_in[10]; const float* bk_i = (const float*)d_in[11];
    const float* Wv_t = (const float*)d_in[12]; const float* bv_t = (const float*)d_in[13];
    const float* Wv_i = (const float*)d_in[14]; const float* bv_i = (const float*)d_in[15];
    const float* Wo_t = (const float*)d_in[16]; const float* bo_t = (const float*)d_in[17];
    const float* Wo_i = (const float*)d_in[18]; const float* bo_i = (const float*)d_in[19];
    const float* ln_g_t = (const float*)d_in[20]; const float* ln_b_t = (const float*)d_in[21];
    const float* ln_g_i = (const float*)d_in[22]; const float* ln_b_i = (const float*)d_in[23];
    const int* split = (const int*)d_in[24];

    float* out = (float*)d_out;

    const int BT = in_sizes[0] / E_DIM;   // B*T = 8192
    const int T_ = 1024;                  // per reference setup
    const int B  = BT / T_;

    float* ws = (float*)d_ws;
    const size_t buf = (size_t)BT * E_DIM;   // 8M floats = 32MB
    float* q_ws = ws;
    float* k_ws = ws + buf;
    float* v_ws = ws + 2 * buf;

    dim3 blk(256);
    dim3 ggrid(E_DIM / GN, BT / GM, 2);

    const float scaling = 0.125f;  // HD^-0.5

    mw_linear_mfma<<<ggrid, blk, 0, stream>>>(query, Wq_t, bq_t, Wq_i, bq_i, q_ws, split, scaling, T_);
    mw_linear_mfma<<<ggrid, blk, 0, stream>>>(key,   Wk_t, bk_t, Wk_i, bk_i, k_ws, split, 1.0f, T_);
    mw_linear_mfma<<<ggrid, blk, 0, stream>>>(value, Wv_t, bv_t, Wv_i, bv_i, v_ws, split, 1.0f, T_);

    dim3 agrid(T_ / 256, HEADS, B);
    attn_kernel<<<agrid, blk, 0, stream>>>(q_ws, k_ws, v_ws, mask, q_ws, T_);

    mw_ln_kernel<<<dim3(BT), blk, 0, stream>>>(q_ws, ln_g_t, ln_b_t, ln_g_i, ln_b_i, k_ws, split, T_);

    mw_linear_mfma<<<ggrid, blk, 0, stream>>>(k_ws, Wo_t, bo_t, Wo_i, bo_i, out, split, 1.0f, T_);
}

// Round 4
// 615.882 us; speedup vs baseline: 4.2598x; 2.5198x over previous
//
#include <hip/hip_runtime.h>

#define E_DIM 1024
#define HEADS 16
#define HD 64

typedef __attribute__((ext_vector_type(8))) short bf16x8;
typedef __attribute__((ext_vector_type(4))) float floatx4;

// round-half-up fp32 -> bf16, pack two into one dword (lo = a, hi = b)
__device__ inline unsigned int pack2bf(float a, float b) {
    unsigned int ua = __builtin_bit_cast(unsigned int, a);
    unsigned int ub = __builtin_bit_cast(unsigned int, b);
    ua = (ua + 0x8000u) >> 16;
    ub = (ub + 0x8000u) & 0xFFFF0000u;
    return ua | ub;
}
__device__ inline unsigned short f2bf(float a) {
    return (unsigned short)((__builtin_bit_cast(unsigned int, a) + 0x8000u) >> 16);
}

// ---------------------------------------------------------------------------
// Multiway linear, bf16 MFMA (unchanged from round 2).
// ---------------------------------------------------------------------------
#define GM 128
#define GN 128
#define GK 32
#define LDK 40

__global__ __launch_bounds__(256) void mw_linear_mfma(
    const float* __restrict__ x,
    const float* __restrict__ Wt,
    const float* __restrict__ bt,
    const float* __restrict__ Wi,
    const float* __restrict__ bi,
    float* __restrict__ out,
    const int* __restrict__ split_ptr,
    float scale, int T_)
{
    const int split = *split_ptr;
    const int kind = blockIdx.z;
    const int m0 = blockIdx.y * GM;
    const int n0 = blockIdx.x * GN;
    const int t0 = m0 % T_;

    if (kind == 0) { if (t0 >= split) return; }
    else           { if (t0 + GM <= split) return; }

    const float* __restrict__ W    = (kind == 0) ? Wt : Wi;
    const float* __restrict__ bias = (kind == 0) ? bt : bi;

    __shared__ __align__(16) unsigned short As[GM * LDK];
    __shared__ __align__(16) unsigned short Bs[GN * LDK];

    const int tid  = threadIdx.x;
    const int lane = tid & 63;
    const int wv   = tid >> 6;
    const int rw   = (wv >> 1) * 64;
    const int cw   = (wv & 1) * 64;

    const int srow = tid >> 3;
    const int scol = (tid & 7) * 4;

    floatx4 acc[4][4];
    #pragma unroll
    for (int i = 0; i < 4; ++i)
        #pragma unroll
        for (int j = 0; j < 4; ++j)
            acc[i][j] = (floatx4){0.f, 0.f, 0.f, 0.f};

    const int am = lane & 15;
    const int aq = lane >> 4;

    for (int k0 = 0; k0 < E_DIM; k0 += GK) {
        #pragma unroll
        for (int i = 0; i < 4; ++i) {
            int r = srow + i * 32;
            float4 a4 = *(const float4*)&x[(size_t)(m0 + r) * E_DIM + k0 + scol];
            float4 b4 = *(const float4*)&W[(size_t)(n0 + r) * E_DIM + k0 + scol];
            *(unsigned int*)&As[r * LDK + scol]     = pack2bf(a4.x, a4.y);
            *(unsigned int*)&As[r * LDK + scol + 2] = pack2bf(a4.z, a4.w);
            *(unsigned int*)&Bs[r * LDK + scol]     = pack2bf(b4.x, b4.y);
            *(unsigned int*)&Bs[r * LDK + scol + 2] = pack2bf(b4.z, b4.w);
        }
        __syncthreads();

        bf16x8 af[4], bfv[4];
        #pragma unroll
        for (int i = 0; i < 4; ++i)
            af[i] = *(const bf16x8*)&As[(rw + i * 16 + am) * LDK + aq * 8];
        #pragma unroll
        for (int j = 0; j < 4; ++j)
            bfv[j] = *(const bf16x8*)&Bs[(cw + j * 16 + am) * LDK + aq * 8];

        #pragma unroll
        for (int i = 0; i < 4; ++i)
            #pragma unroll
            for (int j = 0; j < 4; ++j)
                acc[i][j] = __builtin_amdgcn_mfma_f32_16x16x32_bf16(af[i], bfv[j], acc[i][j], 0, 0, 0);
        __syncthreads();
    }

    const int cq = lane >> 4;
    const int cm = lane & 15;
    #pragma unroll
    for (int j = 0; j < 4; ++j) {
        int n = n0 + cw + j * 16 + cm;
        float bv = bias[n];
        #pragma unroll
        for (int i = 0; i < 4; ++i) {
            int mbase = m0 + rw + i * 16 + cq * 4;
            #pragma unroll
            for (int r = 0; r < 4; ++r) {
                int m = mbase + r;
                int t = m % T_;
                if (((t < split) ? 0 : 1) != kind) continue;
                out[(size_t)m * E_DIM + n] = (acc[i][j][r] + bv) * scale;
            }
        }
    }
}

// ---------------------------------------------------------------------------
// Flash attention, bf16 MFMA. Block = 64 Q-rows of one (b,h); 4 waves x 16
// rows. K tiles 64 wide. LDS layouts: [chunk(2)][64][40] shorts (GEMM-proven
// bank pattern). V stored transposed with row permutation d^((d>>4)&3).
// P round-trip wave-private with col-granule XOR swizzle (key = row quad).
// Output written in place over q (block-exclusive region).
// ---------------------------------------------------------------------------
__global__ __launch_bounds__(256) void attn_mfma(
    const float* __restrict__ q, const float* __restrict__ k, const float* __restrict__ v,
    const float* __restrict__ mask, float* __restrict__ outp, int T_)
{
    const int tid  = threadIdx.x;
    const int lane = tid & 63;
    const int wv   = tid >> 6;
    const int h    = blockIdx.y;
    const int b    = blockIdx.z;
    const int r0   = blockIdx.x * 64;

    __shared__ __align__(16) unsigned short Qs[2 * 64 * 40];
    __shared__ __align__(16) unsigned short Ks[2 * 64 * 40];
    __shared__ __align__(16) unsigned short Vst[2 * 64 * 40];
    __shared__ __align__(16) unsigned short Ps[4 * 2 * 16 * 40];

    const int m    = lane & 15;   // fragment row/col within 16
    const int kq   = lane >> 4;   // k-quad
    const int wrow = wv * 16;

    // ---- stage Q tile (rows r0..r0+63, cols h*64..+64) ----
    #pragma unroll
    for (int i = 0; i < 4; ++i) {
        int f   = tid + 256 * i;
        int row = f >> 4;
        int c4  = (f & 15) * 4;
        float4 a4 = *(const float4*)&q[((size_t)(b * T_ + r0 + row)) * E_DIM + h * HD + c4];
        int ad = (c4 >> 5) * 2560 + row * 40 + (c4 & 31);
        *(unsigned int*)&Qs[ad]     = pack2bf(a4.x, a4.y);
        *(unsigned int*)&Qs[ad + 2] = pack2bf(a4.z, a4.w);
    }
    __syncthreads();

    bf16x8 aq[2];
    aq[0] = *(const bf16x8*)&Qs[0 * 2560 + (wrow + m) * 40 + kq * 8];
    aq[1] = *(const bf16x8*)&Qs[1 * 2560 + (wrow + m) * 40 + kq * 8];

    floatx4 oa[4];
    #pragma unroll
    for (int j = 0; j < 4; ++j) oa[j] = (floatx4){0.f, 0.f, 0.f, 0.f};
    float mrun[4] = {-3.0e38f, -3.0e38f, -3.0e38f, -3.0e38f};
    float lsum[4] = {0.f, 0.f, 0.f, 0.f};

    // V-transpose staging coords: thread handles 4s x 4d micro-tile
    const int vs0 = (tid >> 4) * 4;
    const int vd0 = (tid & 15) * 4;

    #pragma unroll 1
    for (int s0 = 0; s0 < T_; s0 += 64) {
        __syncthreads();   // prior iteration's frag reads done before restage

        // stage K tile (normal layout)
        #pragma unroll
        for (int i = 0; i < 4; ++i) {
            int f   = tid + 256 * i;
            int row = f >> 4;
            int c4  = (f & 15) * 4;
            float4 a4 = *(const float4*)&k[((size_t)(b * T_ + s0 + row)) * E_DIM + h * HD + c4];
            int ad = (c4 >> 5) * 2560 + row * 40 + (c4 & 31);
            *(unsigned int*)&Ks[ad]     = pack2bf(a4.x, a4.y);
            *(unsigned int*)&Ks[ad + 2] = pack2bf(a4.z, a4.w);
        }

        // stage V tile transposed (register micro-tile transpose)
        {
            float4 vvr[4];
            #pragma unroll
            for (int i = 0; i < 4; ++i)
                vvr[i] = *(const float4*)&v[((size_t)(b * T_ + s0 + vs0 + i)) * E_DIM + h * HD + vd0];
            const float* vp = (const float*)vvr;
            int plane = (vs0 >> 5) * 2560;
            int sin   = vs0 & 31;
            #pragma unroll
            for (int t = 0; t < 4; ++t) {
                int d  = vd0 + t;
                int pr = d ^ ((d >> 4) & 3);
                uint2 w;
                w.x = pack2bf(vp[0 * 4 + t], vp[1 * 4 + t]);
                w.y = pack2bf(vp[2 * 4 + t], vp[3 * 4 + t]);
                *(uint2*)&Vst[plane + pr * 40 + sin] = w;
            }
        }

        // mask prefetch: rows r0+wrow+kq*4+r, cols s0 + j*16 + m
        float mv[4][4];
        {
            const float* mbase = &mask[(size_t)(r0 + wrow + kq * 4) * T_ + s0 + m];
            #pragma unroll
            for (int j = 0; j < 4; ++j)
                #pragma unroll
                for (int r = 0; r < 4; ++r)
                    mv[j][r] = mbase[r * T_ + j * 16];
        }

        __syncthreads();

        // ---- QK^T : S[16 x 64] per wave ----
        floatx4 sa[4];
        #pragma unroll
        for (int j = 0; j < 4; ++j) sa[j] = (floatx4){0.f, 0.f, 0.f, 0.f};
        #pragma unroll
        for (int c = 0; c < 2; ++c) {
            #pragma unroll
            for (int j = 0; j < 4; ++j) {
                bf16x8 bk = *(const bf16x8*)&Ks[c * 2560 + (j * 16 + m) * 40 + kq * 8];
                sa[j] = __builtin_amdgcn_mfma_f32_16x16x32_bf16(aq[c], bk, sa[j], 0, 0, 0);
            }
        }

        // ---- online softmax (lane owns rows kq*4+r, cols m of each subtile) --
        float mnew[4], alpha[4];
        #pragma unroll
        for (int r = 0; r < 4; ++r) {
            sa[0][r] += mv[0][r]; sa[1][r] += mv[1][r];
            sa[2][r] += mv[2][r]; sa[3][r] += mv[3][r];
            float mt = fmaxf(fmaxf(sa[0][r], sa[1][r]), fmaxf(sa[2][r], sa[3][r]));
            mt = fmaxf(mt, __shfl_xor(mt, 1));
            mt = fmaxf(mt, __shfl_xor(mt, 2));
            mt = fmaxf(mt, __shfl_xor(mt, 4));
            mt = fmaxf(mt, __shfl_xor(mt, 8));
            float mn = fmaxf(mrun[r], mt);
            alpha[r] = __expf(mrun[r] - mn);
            mnew[r] = mn;          // <-- round-3 bug: was never assigned
            mrun[r] = mn;
        }
        #pragma unroll
        for (int j = 0; j < 4; ++j)
            #pragma unroll
            for (int r = 0; r < 4; ++r)
                oa[j][r] *= alpha[r];

        float rs[4] = {0.f, 0.f, 0.f, 0.f};
        #pragma unroll
        for (int j = 0; j < 4; ++j) {
            int gl = ((((j & 1) << 1) | (m >> 3)) ^ kq) & 3;
            int pbase = wv * 1280 + (j >> 1) * 640 + (kq * 4) * 40 + gl * 8 + (m & 7);
            #pragma unroll
            for (int r = 0; r < 4; ++r) {
                float p = __expf(sa[j][r] - mnew[r]);
                rs[r] += p;
                Ps[pbase + r * 40] = f2bf(p);
            }
        }
        #pragma unroll
        for (int r = 0; r < 4; ++r) {
            float s = rs[r];
            s += __shfl_xor(s, 1); s += __shfl_xor(s, 2);
            s += __shfl_xor(s, 4); s += __shfl_xor(s, 8);
            lsum[r] = lsum[r] * alpha[r] + s;
        }

        // ---- PV : O[16 x 64] accumulate (wave-private P readback) ----
        #pragma unroll
        for (int c = 0; c < 2; ++c) {
            bf16x8 ap = *(const bf16x8*)&Ps[wv * 1280 + c * 640 + m * 40 + ((kq ^ (m >> 2)) & 3) * 8];
            #pragma unroll
            for (int j = 0; j < 4; ++j) {
                int pr = 16 * j + (m ^ j);
                bf16x8 bv = *(const bf16x8*)&Vst[c * 2560 + pr * 40 + kq * 8];
                oa[j] = __builtin_amdgcn_mfma_f32_16x16x32_bf16(ap, bv, oa[j], 0, 0, 0);
            }
        }
    }

    // ---- epilogue: normalize and store (in place over q region) ----
    #pragma unroll
    for (int r = 0; r < 4; ++r) {
        float inv = 1.0f / lsum[r];
        size_t orow = ((size_t)(b * T_ + r0 + wrow + kq * 4 + r)) * E_DIM + h * HD;
        #pragma unroll
        for (int j = 0; j < 4; ++j)
            outp[orow + j * 16 + m] = oa[j][r] * inv;
    }
}

// ---------------------------------------------------------------------------
// Multiway LayerNorm over rows of (R, 1024). One block (256 thr) per row.
// ---------------------------------------------------------------------------
__global__ __launch_bounds__(256) void mw_ln_kernel(
    const float* __restrict__ x,
    const float* __restrict__ gt, const float* __restrict__ bt,
    const float* __restrict__ gi, const float* __restrict__ bi,
    float* __restrict__ out,
    const int* __restrict__ split_ptr, int T_)
{
    const int split = *split_ptr;
    const int row = blockIdx.x;
    const int t = row % T_;
    const float* __restrict__ g  = (t < split) ? gt : gi;
    const float* __restrict__ bb = (t < split) ? bt : bi;

    const int tid = threadIdx.x;
    const int lane = tid & 63;
    const int wid = tid >> 6;

    __shared__ float red[8];

    float4 xv = *(const float4*)&x[(size_t)row * E_DIM + tid * 4];
    float s = xv.x + xv.y + xv.z + xv.w;
    #pragma unroll
    for (int off = 1; off < 64; off <<= 1) s += __shfl_xor(s, off, 64);
    if (lane == 0) red[wid] = s;
    __syncthreads();
    float mu = (red[0] + red[1] + red[2] + red[3]) * (1.0f / E_DIM);

    float4 d;
    d.x = xv.x - mu; d.y = xv.y - mu; d.z = xv.z - mu; d.w = xv.w - mu;
    float s2 = d.x*d.x + d.y*d.y + d.z*d.z + d.w*d.w;
    #pragma unroll
    for (int off = 1; off < 64; off <<= 1) s2 += __shfl_xor(s2, off, 64);
    if (lane == 0) red[4 + wid] = s2;
    __syncthreads();
    float var = (red[4] + red[5] + red[6] + red[7]) * (1.0f / E_DIM);
    float rstd = rsqrtf(var + 1e-5f);

    float4 gv = *(const float4*)&g[tid * 4];
    float4 bv = *(const float4*)&bb[tid * 4];
    float4 ov;
    ov.x = d.x * rstd * gv.x + bv.x;
    ov.y = d.y * rstd * gv.y + bv.y;
    ov.z = d.z * rstd * gv.z + bv.z;
    ov.w = d.w * rstd * gv.w + bv.w;
    *(float4*)&out[(size_t)row * E_DIM + tid * 4] = ov;
}

// ---------------------------------------------------------------------------
extern "C" void kernel_launch(void* const* d_in, const int* in_sizes, int n_in,
                              void* d_out, int out_size, void* d_ws, size_t ws_size,
                              hipStream_t stream) {
    const float* query = (const float*)d_in[0];
    const float* key   = (const float*)d_in[1];
    const float* value = (const float*)d_in[2];
    const float* mask  = (const float*)d_in[3];
    const float* Wq_t = (const float*)d_in[4];  const float* bq_t = (const float*)d_in[5];
    const float* Wq_i = (const float*)d_in[6];  const float* bq_i = (const float*)d_in[7];
    const float* Wk_t = (const float*)d_in[8];  const float* bk_t = (const float*)d_in[9];
    const float* Wk_i = (const float*)d_in[10]; const float* bk_i = (const float*)d_in[11];
    const float* Wv_t = (const float*)d_in[12]; const float* bv_t = (const float*)d_in[13];
    const float* Wv_i = (const float*)d_in[14]; const float* bv_i = (const float*)d_in[15];
    const float* Wo_t = (const float*)d_in[16]; const float* bo_t = (const float*)d_in[17];
    const float* Wo_i = (const float*)d_in[18]; const float* bo_i = (const float*)d_in[19];
    const float* ln_g_t = (const float*)d_in[20]; const float* ln_b_t = (const float*)d_in[21];
    const float* ln_g_i = (const float*)d_in[22]; const float* ln_b_i = (const float*)d_in[23];
    const int* split = (const int*)d_in[24];

    float* out = (float*)d_out;

    const int BT = in_sizes[0] / E_DIM;   // B*T = 8192
    const int T_ = 1024;
    const int B  = BT / T_;

    float* ws = (float*)d_ws;
    const size_t buf = (size_t)BT * E_DIM;
    float* q_ws = ws;
    float* k_ws = ws + buf;
    float* v_ws = ws + 2 * buf;

    dim3 blk(256);
    dim3 ggrid(E_DIM / GN, BT / GM, 2);

    const float scaling = 0.125f;  // HD^-0.5

    mw_linear_mfma<<<ggrid, blk, 0, stream>>>(query, Wq_t, bq_t, Wq_i, bq_i, q_ws, split, scaling, T_);
    mw_linear_mfma<<<ggrid, blk, 0, stream>>>(key,   Wk_t, bk_t, Wk_i, bk_i, k_ws, split, 1.0f, T_);
    mw_linear_mfma<<<ggrid, blk, 0, stream>>>(value, Wv_t, bv_t, Wv_i, bv_i, v_ws, split, 1.0f, T_);

    dim3 agrid(T_ / 64, HEADS, B);
    attn_mfma<<<agrid, blk, 0, stream>>>(q_ws, k_ws, v_ws, mask, q_ws, T_);

    mw_ln_kernel<<<dim3(BT), blk, 0, stream>>>(q_ws, ln_g_t, ln_b_t, ln_g_i, ln_b_i, k_ws, split, T_);

    mw_linear_mfma<<<ggrid, blk, 0, stream>>>(k_ws, Wo_t, bo_t, Wo_i, bo_i, out, split, 1.0f, T_);
}

// Round 5
// 523.995 us; speedup vs baseline: 5.0068x; 1.1754x over previous
//
#include <hip/hip_runtime.h>

#define E_DIM 1024
#define HEADS 16
#define HD 64

typedef unsigned short ushort_t;
typedef __attribute__((ext_vector_type(8))) short bf16x8;
typedef __attribute__((ext_vector_type(4))) float floatx4;

// round-half-up fp32 -> bf16 helpers
__device__ inline unsigned int pack2bf(float a, float b) {
    unsigned int ua = __builtin_bit_cast(unsigned int, a);
    unsigned int ub = __builtin_bit_cast(unsigned int, b);
    ua = (ua + 0x8000u) >> 16;
    ub = (ub + 0x8000u) & 0xFFFF0000u;
    return ua | ub;
}
__device__ inline unsigned short f2bf(float a) {
    return (unsigned short)((__builtin_bit_cast(unsigned int, a) + 0x8000u) >> 16);
}
__device__ inline float bf2f(unsigned int s) {
    return __builtin_bit_cast(float, s << 16);
}

// async global->LDS, 16B per lane; LDS dest = wave-uniform base + lane*16
__device__ __forceinline__ void load_lds16(const void* g, void* l) {
    __builtin_amdgcn_global_load_lds(
        (const __attribute__((address_space(1))) unsigned int*)g,
        (__attribute__((address_space(3))) unsigned int*)l, 16, 0, 0);
}

// ---------------------------------------------------------------------------
// fp32 -> bf16 conversion (elementwise, 8 elems/thread)
// ---------------------------------------------------------------------------
__global__ __launch_bounds__(256) void cvt_f32_bf16(
    const float* __restrict__ in, ushort_t* __restrict__ out)
{
    size_t i = ((size_t)blockIdx.x * 256 + threadIdx.x) * 8;
    float4 a = *(const float4*)&in[i];
    float4 b = *(const float4*)&in[i + 4];
    uint4 o;
    o.x = pack2bf(a.x, a.y); o.y = pack2bf(a.z, a.w);
    o.z = pack2bf(b.x, b.y); o.w = pack2bf(b.z, b.w);
    *(uint4*)&out[i] = o;
}

__global__ __launch_bounds__(256) void cvt_weights(
    const float* w0, const float* w1, const float* w2, const float* w3,
    const float* w4, const float* w5, const float* w6, const float* w7,
    ushort_t* __restrict__ out)
{
    const float* srcs[8] = {w0, w1, w2, w3, w4, w5, w6, w7};
    const float* __restrict__ src = srcs[blockIdx.y];
    ushort_t* __restrict__ dst = out + (size_t)blockIdx.y * E_DIM * E_DIM;
    size_t i = ((size_t)blockIdx.x * 256 + threadIdx.x) * 8;
    float4 a = *(const float4*)&src[i];
    float4 b = *(const float4*)&src[i + 4];
    uint4 o;
    o.x = pack2bf(a.x, a.y); o.y = pack2bf(a.z, a.w);
    o.z = pack2bf(b.x, b.y); o.w = pack2bf(b.z, b.w);
    *(uint4*)&dst[i] = o;
}

// ---------------------------------------------------------------------------
// Multiway linear, bf16-in MFMA with global_load_lds staging (m97 recipe).
// 128x128 tile, BK=32, 4 waves (2x2 of 64x64). LDS unpadded [128][32] shorts.
// OUT_BF16: store bf16 (for q/k/v); else fp32 (final projection).
// ---------------------------------------------------------------------------
template<bool OUT_BF16>
__global__ __launch_bounds__(256) void gemm_mw(
    const ushort_t* __restrict__ x,    // (R, E) bf16
    const ushort_t* __restrict__ Wt,   // (E, E) bf16, C = x @ W^T
    const float* __restrict__ bt,
    const ushort_t* __restrict__ Wi,
    const float* __restrict__ bi,
    void* __restrict__ outv,           // (R, E)
    const int* __restrict__ split_ptr,
    float scale, int T_)
{
    const int split = *split_ptr;
    const int kind = blockIdx.z;
    const int m0 = blockIdx.y * 128;
    const int n0 = blockIdx.x * 128;
    const int t0 = m0 % T_;

    if (kind == 0) { if (t0 >= split) return; }
    else           { if (t0 + 128 <= split) return; }

    const ushort_t* __restrict__ W    = (kind == 0) ? Wt : Wi;
    const float*    __restrict__ bias = (kind == 0) ? bt : bi;

    __shared__ __align__(16) ushort_t As[128 * 32];
    __shared__ __align__(16) ushort_t Bs[128 * 32];

    const int tid  = threadIdx.x;
    const int lane = tid & 63;
    const int wv   = tid >> 6;
    const int rw   = (wv >> 1) * 64;
    const int cw   = (wv & 1) * 64;
    const int am   = lane & 15;
    const int aq   = lane >> 4;

    // staging: wave wv covers tile rows [wv*32, wv*32+32); lane -> row l/4, col (l&3)*8
    const int grow = wv * 32 + (lane >> 2);
    const int gcol = (lane & 3) * 8;

    floatx4 acc[4][4];
    #pragma unroll
    for (int i = 0; i < 4; ++i)
        #pragma unroll
        for (int j = 0; j < 4; ++j)
            acc[i][j] = (floatx4){0.f, 0.f, 0.f, 0.f};

    for (int k0 = 0; k0 < E_DIM; k0 += 32) {
        load_lds16(&x[(size_t)(m0 + grow) * E_DIM + k0 + gcol],      &As[(wv * 32) * 32]);
        load_lds16(&x[(size_t)(m0 + grow + 16) * E_DIM + k0 + gcol], &As[(wv * 32 + 16) * 32]);
        load_lds16(&W[(size_t)(n0 + grow) * E_DIM + k0 + gcol],      &Bs[(wv * 32) * 32]);
        load_lds16(&W[(size_t)(n0 + grow + 16) * E_DIM + k0 + gcol], &Bs[(wv * 32 + 16) * 32]);
        __syncthreads();

        bf16x8 af[4], bfv[4];
        #pragma unroll
        for (int i = 0; i < 4; ++i)
            af[i] = *(const bf16x8*)&As[(rw + i * 16 + am) * 32 + aq * 8];
        #pragma unroll
        for (int j = 0; j < 4; ++j)
            bfv[j] = *(const bf16x8*)&Bs[(cw + j * 16 + am) * 32 + aq * 8];

        #pragma unroll
        for (int i = 0; i < 4; ++i)
            #pragma unroll
            for (int j = 0; j < 4; ++j)
                acc[i][j] = __builtin_amdgcn_mfma_f32_16x16x32_bf16(af[i], bfv[j], acc[i][j], 0, 0, 0);
        __syncthreads();
    }

    // C/D layout: col = lane&15, row = (lane>>4)*4 + reg
    const int cq = lane >> 4;
    const int cm = lane & 15;
    #pragma unroll
    for (int j = 0; j < 4; ++j) {
        int n = n0 + cw + j * 16 + cm;
        float bv = bias[n];
        #pragma unroll
        for (int i = 0; i < 4; ++i) {
            int mbase = m0 + rw + i * 16 + cq * 4;
            #pragma unroll
            for (int r = 0; r < 4; ++r) {
                int m = mbase + r;
                int t = m % T_;
                if (((t < split) ? 0 : 1) != kind) continue;
                float val = (acc[i][j][r] + bv) * scale;
                if (OUT_BF16) ((ushort_t*)outv)[(size_t)m * E_DIM + n] = f2bf(val);
                else          ((float*)outv)[(size_t)m * E_DIM + n] = val;
            }
        }
    }
}

// ---------------------------------------------------------------------------
// Flash attention, bf16 MFMA (layouts identical to round 4; bf16 I/O).
// Block = 64 Q-rows of one (b,h); 4 waves x 16 rows. Output in place over q.
// ---------------------------------------------------------------------------
__global__ __launch_bounds__(256) void attn_mfma(
    const ushort_t* __restrict__ q, const ushort_t* __restrict__ k,
    const ushort_t* __restrict__ v, const float* __restrict__ mask,
    ushort_t* __restrict__ outp, int T_)
{
    const int tid  = threadIdx.x;
    const int lane = tid & 63;
    const int wv   = tid >> 6;
    const int h    = blockIdx.y;
    const int b    = blockIdx.z;
    const int r0   = blockIdx.x * 64;

    __shared__ __align__(16) unsigned short Qs[2 * 64 * 40];
    __shared__ __align__(16) unsigned short Ks[2 * 64 * 40];
    __shared__ __align__(16) unsigned short Vst[2 * 64 * 40];
    __shared__ __align__(16) unsigned short Ps[4 * 2 * 16 * 40];

    const int m    = lane & 15;
    const int kq   = lane >> 4;
    const int wrow = wv * 16;

    // ---- stage Q tile ----
    #pragma unroll
    for (int i = 0; i < 4; ++i) {
        int f   = tid + 256 * i;
        int row = f >> 4;
        int c4  = (f & 15) * 4;
        uint2 a2 = *(const uint2*)&q[((size_t)(b * T_ + r0 + row)) * E_DIM + h * HD + c4];
        int ad = (c4 >> 5) * 2560 + row * 40 + (c4 & 31);
        *(unsigned int*)&Qs[ad]     = a2.x;
        *(unsigned int*)&Qs[ad + 2] = a2.y;
    }
    __syncthreads();

    bf16x8 aq[2];
    aq[0] = *(const bf16x8*)&Qs[0 * 2560 + (wrow + m) * 40 + kq * 8];
    aq[1] = *(const bf16x8*)&Qs[1 * 2560 + (wrow + m) * 40 + kq * 8];

    floatx4 oa[4];
    #pragma unroll
    for (int j = 0; j < 4; ++j) oa[j] = (floatx4){0.f, 0.f, 0.f, 0.f};
    float mrun[4] = {-3.0e38f, -3.0e38f, -3.0e38f, -3.0e38f};
    float lsum[4] = {0.f, 0.f, 0.f, 0.f};

    const int vs0 = (tid >> 4) * 4;
    const int vd0 = (tid & 15) * 4;

    #pragma unroll 1
    for (int s0 = 0; s0 < T_; s0 += 64) {
        __syncthreads();

        // stage K tile (normal layout)
        #pragma unroll
        for (int i = 0; i < 4; ++i) {
            int f   = tid + 256 * i;
            int row = f >> 4;
            int c4  = (f & 15) * 4;
            uint2 a2 = *(const uint2*)&k[((size_t)(b * T_ + s0 + row)) * E_DIM + h * HD + c4];
            int ad = (c4 >> 5) * 2560 + row * 40 + (c4 & 31);
            *(unsigned int*)&Ks[ad]     = a2.x;
            *(unsigned int*)&Ks[ad + 2] = a2.y;
        }

        // stage V tile transposed (register micro-tile transpose)
        {
            uint2 vvr[4];
            #pragma unroll
            for (int i = 0; i < 4; ++i)
                vvr[i] = *(const uint2*)&v[((size_t)(b * T_ + s0 + vs0 + i)) * E_DIM + h * HD + vd0];
            const ushort_t* vp = (const ushort_t*)vvr;
            int plane = (vs0 >> 5) * 2560;
            int sin   = vs0 & 31;
            #pragma unroll
            for (int t = 0; t < 4; ++t) {
                int d  = vd0 + t;
                int pr = d ^ ((d >> 4) & 3);
                uint2 w;
                w.x = (unsigned int)vp[0 * 4 + t] | ((unsigned int)vp[1 * 4 + t] << 16);
                w.y = (unsigned int)vp[2 * 4 + t] | ((unsigned int)vp[3 * 4 + t] << 16);
                *(uint2*)&Vst[plane + pr * 40 + sin] = w;
            }
        }

        // mask prefetch
        float mv[4][4];
        {
            const float* mbase = &mask[(size_t)(r0 + wrow + kq * 4) * T_ + s0 + m];
            #pragma unroll
            for (int j = 0; j < 4; ++j)
                #pragma unroll
                for (int r = 0; r < 4; ++r)
                    mv[j][r] = mbase[r * T_ + j * 16];
        }

        __syncthreads();

        // ---- QK^T ----
        floatx4 sa[4];
        #pragma unroll
        for (int j = 0; j < 4; ++j) sa[j] = (floatx4){0.f, 0.f, 0.f, 0.f};
        #pragma unroll
        for (int c = 0; c < 2; ++c) {
            #pragma unroll
            for (int j = 0; j < 4; ++j) {
                bf16x8 bk = *(const bf16x8*)&Ks[c * 2560 + (j * 16 + m) * 40 + kq * 8];
                sa[j] = __builtin_amdgcn_mfma_f32_16x16x32_bf16(aq[c], bk, sa[j], 0, 0, 0);
            }
        }

        // ---- online softmax ----
        float mnew[4], alpha[4];
        #pragma unroll
        for (int r = 0; r < 4; ++r) {
            sa[0][r] += mv[0][r]; sa[1][r] += mv[1][r];
            sa[2][r] += mv[2][r]; sa[3][r] += mv[3][r];
            float mt = fmaxf(fmaxf(sa[0][r], sa[1][r]), fmaxf(sa[2][r], sa[3][r]));
            mt = fmaxf(mt, __shfl_xor(mt, 1));
            mt = fmaxf(mt, __shfl_xor(mt, 2));
            mt = fmaxf(mt, __shfl_xor(mt, 4));
            mt = fmaxf(mt, __shfl_xor(mt, 8));
            float mn = fmaxf(mrun[r], mt);
            alpha[r] = __expf(mrun[r] - mn);
            mnew[r] = mn;
            mrun[r] = mn;
        }
        #pragma unroll
        for (int j = 0; j < 4; ++j)
            #pragma unroll
            for (int r = 0; r < 4; ++r)
                oa[j][r] *= alpha[r];

        float rs[4] = {0.f, 0.f, 0.f, 0.f};
        #pragma unroll
        for (int j = 0; j < 4; ++j) {
            int gl = ((((j & 1) << 1) | (m >> 3)) ^ kq) & 3;
            int pbase = wv * 1280 + (j >> 1) * 640 + (kq * 4) * 40 + gl * 8 + (m & 7);
            #pragma unroll
            for (int r = 0; r < 4; ++r) {
                float p = __expf(sa[j][r] - mnew[r]);
                rs[r] += p;
                Ps[pbase + r * 40] = f2bf(p);
            }
        }
        #pragma unroll
        for (int r = 0; r < 4; ++r) {
            float s = rs[r];
            s += __shfl_xor(s, 1); s += __shfl_xor(s, 2);
            s += __shfl_xor(s, 4); s += __shfl_xor(s, 8);
            lsum[r] = lsum[r] * alpha[r] + s;
        }

        // ---- PV ----
        #pragma unroll
        for (int c = 0; c < 2; ++c) {
            bf16x8 ap = *(const bf16x8*)&Ps[wv * 1280 + c * 640 + m * 40 + ((kq ^ (m >> 2)) & 3) * 8];
            #pragma unroll
            for (int j = 0; j < 4; ++j) {
                int pr = 16 * j + (m ^ j);
                bf16x8 bv = *(const bf16x8*)&Vst[c * 2560 + pr * 40 + kq * 8];
                oa[j] = __builtin_amdgcn_mfma_f32_16x16x32_bf16(ap, bv, oa[j], 0, 0, 0);
            }
        }
    }

    // ---- epilogue (bf16, in place over q region) ----
    #pragma unroll
    for (int r = 0; r < 4; ++r) {
        float inv = 1.0f / lsum[r];
        size_t orow = ((size_t)(b * T_ + r0 + wrow + kq * 4 + r)) * E_DIM + h * HD;
        #pragma unroll
        for (int j = 0; j < 4; ++j)
            outp[orow + j * 16 + m] = f2bf(oa[j][r] * inv);
    }
}

// ---------------------------------------------------------------------------
// Multiway LayerNorm, bf16 in / bf16 out, fp32 stats. One block per row.
// ---------------------------------------------------------------------------
__global__ __launch_bounds__(256) void mw_ln_bf16(
    const ushort_t* __restrict__ x,
    const float* __restrict__ gt, const float* __restrict__ bt,
    const float* __restrict__ gi, const float* __restrict__ bi,
    ushort_t* __restrict__ out,
    const int* __restrict__ split_ptr, int T_)
{
    const int split = *split_ptr;
    const int row = blockIdx.x;
    const int t = row % T_;
    const float* __restrict__ g  = (t < split) ? gt : gi;
    const float* __restrict__ bb = (t < split) ? bt : bi;

    const int tid = threadIdx.x;
    const int lane = tid & 63;
    const int wid = tid >> 6;

    __shared__ float red[8];

    uint2 xv = *(const uint2*)&x[(size_t)row * E_DIM + tid * 4];
    float f0 = bf2f(xv.x & 0xffffu), f1 = bf2f(xv.x >> 16);
    float f2 = bf2f(xv.y & 0xffffu), f3 = bf2f(xv.y >> 16);
    float s = f0 + f1 + f2 + f3;
    #pragma unroll
    for (int off = 1; off < 64; off <<= 1) s += __shfl_xor(s, off, 64);
    if (lane == 0) red[wid] = s;
    __syncthreads();
    float mu = (red[0] + red[1] + red[2] + red[3]) * (1.0f / E_DIM);

    float d0 = f0 - mu, d1 = f1 - mu, d2 = f2 - mu, d3 = f3 - mu;
    float s2 = d0*d0 + d1*d1 + d2*d2 + d3*d3;
    #pragma unroll
    for (int off = 1; off < 64; off <<= 1) s2 += __shfl_xor(s2, off, 64);
    if (lane == 0) red[4 + wid] = s2;
    __syncthreads();
    float var = (red[4] + red[5] + red[6] + red[7]) * (1.0f / E_DIM);
    float rstd = rsqrtf(var + 1e-5f);

    float4 gv = *(const float4*)&g[tid * 4];
    float4 bv = *(const float4*)&bb[tid * 4];
    uint2 ov;
    ov.x = pack2bf(d0 * rstd * gv.x + bv.x, d1 * rstd * gv.y + bv.y);
    ov.y = pack2bf(d2 * rstd * gv.z + bv.z, d3 * rstd * gv.w + bv.w);
    *(uint2*)&out[(size_t)row * E_DIM + tid * 4] = ov;
}

// ---------------------------------------------------------------------------
extern "C" void kernel_launch(void* const* d_in, const int* in_sizes, int n_in,
                              void* d_out, int out_size, void* d_ws, size_t ws_size,
                              hipStream_t stream) {
    const float* query = (const float*)d_in[0];
    const float* key   = (const float*)d_in[1];
    const float* value = (const float*)d_in[2];
    const float* mask  = (const float*)d_in[3];
    const float* Wq_t = (const float*)d_in[4];  const float* bq_t = (const float*)d_in[5];
    const float* Wq_i = (const float*)d_in[6];  const float* bq_i = (const float*)d_in[7];
    const float* Wk_t = (const float*)d_in[8];  const float* bk_t = (const float*)d_in[9];
    const float* Wk_i = (const float*)d_in[10]; const float* bk_i = (const float*)d_in[11];
    const float* Wv_t = (const float*)d_in[12]; const float* bv_t = (const float*)d_in[13];
    const float* Wv_i = (const float*)d_in[14]; const float* bv_i = (const float*)d_in[15];
    const float* Wo_t = (const float*)d_in[16]; const float* bo_t = (const float*)d_in[17];
    const float* Wo_i = (const float*)d_in[18]; const float* bo_i = (const float*)d_in[19];
    const float* ln_g_t = (const float*)d_in[20]; const float* ln_b_t = (const float*)d_in[21];
    const float* ln_g_i = (const float*)d_in[22]; const float* ln_b_i = (const float*)d_in[23];
    const int* split = (const int*)d_in[24];

    float* out = (float*)d_out;

    const int BT = in_sizes[0] / E_DIM;   // B*T = 8192
    const int T_ = 1024;
    const int B  = BT / T_;

    ushort_t* ws = (ushort_t*)d_ws;
    const size_t nx = (size_t)BT * E_DIM;        // 8M elements
    const size_t nw = (size_t)E_DIM * E_DIM;     // 1M elements
    ushort_t* x_bf = ws;                 // converted input; later LN output
    ushort_t* q_bf = ws + nx;            // q; later attn output (in place)
    ushort_t* k_bf = ws + 2 * nx;
    ushort_t* v_bf = ws + 3 * nx;
    ushort_t* w_bf = ws + 4 * nx;        // 8 converted weights

    dim3 blk(256);
    dim3 ggrid(E_DIM / 128, BT / 128, 2);
    dim3 agrid(T_ / 64, HEADS, B);
    const int cvt_blocks = (int)(nx / 2048);     // 8 elems/thread, 256 thr
    const int wcvt_blocks = (int)(nw / 2048);
    const float scaling = 0.125f;  // HD^-0.5

    cvt_weights<<<dim3(wcvt_blocks, 8), blk, 0, stream>>>(
        Wq_t, Wq_i, Wk_t, Wk_i, Wv_t, Wv_i, Wo_t, Wo_i, w_bf);

    cvt_f32_bf16<<<cvt_blocks, blk, 0, stream>>>(query, x_bf);
    gemm_mw<true><<<ggrid, blk, 0, stream>>>(x_bf, w_bf + 0 * nw, bq_t, w_bf + 1 * nw, bq_i,
                                             q_bf, split, scaling, T_);
    cvt_f32_bf16<<<cvt_blocks, blk, 0, stream>>>(key, x_bf);
    gemm_mw<true><<<ggrid, blk, 0, stream>>>(x_bf, w_bf + 2 * nw, bk_t, w_bf + 3 * nw, bk_i,
                                             k_bf, split, 1.0f, T_);
    cvt_f32_bf16<<<cvt_blocks, blk, 0, stream>>>(value, x_bf);
    gemm_mw<true><<<ggrid, blk, 0, stream>>>(x_bf, w_bf + 4 * nw, bv_t, w_bf + 5 * nw, bv_i,
                                             v_bf, split, 1.0f, T_);

    attn_mfma<<<agrid, blk, 0, stream>>>(q_bf, k_bf, v_bf, mask, q_bf, T_);

    mw_ln_bf16<<<dim3(BT), blk, 0, stream>>>(q_bf, ln_g_t, ln_b_t, ln_g_i, ln_b_i, x_bf, split, T_);

    gemm_mw<false><<<ggrid, blk, 0, stream>>>(x_bf, w_bf + 6 * nw, bo_t, w_bf + 7 * nw, bo_i,
                                              out, split, 1.0f, T_);
}

// Round 6
// 503.234 us; speedup vs baseline: 5.2133x; 1.0413x over previous
//
#include <hip/hip_runtime.h>

#define E_DIM 1024
#define HEADS 16
#define HD 64

typedef unsigned short ushort_t;
typedef __attribute__((ext_vector_type(8))) short bf16x8;
typedef __attribute__((ext_vector_type(4))) float floatx4;

__device__ inline unsigned int pack2bf(float a, float b) {
    unsigned int ua = __builtin_bit_cast(unsigned int, a);
    unsigned int ub = __builtin_bit_cast(unsigned int, b);
    ua = (ua + 0x8000u) >> 16;
    ub = (ub + 0x8000u) & 0xFFFF0000u;
    return ua | ub;
}
__device__ inline unsigned short f2bf(float a) {
    return (unsigned short)((__builtin_bit_cast(unsigned int, a) + 0x8000u) >> 16);
}
__device__ inline float bf2f(unsigned int s) {
    return __builtin_bit_cast(float, s << 16);
}

__device__ __forceinline__ void load_lds16(const void* g, void* l) {
    __builtin_amdgcn_global_load_lds(
        (const __attribute__((address_space(1))) unsigned int*)g,
        (__attribute__((address_space(3))) unsigned int*)l, 16, 0, 0);
}

// ---------------------------------------------------------------------------
// fp32 -> bf16 conversions
// ---------------------------------------------------------------------------
__global__ __launch_bounds__(256) void cvt_inputs(
    const float* s0, const float* s1, const float* s2,
    ushort_t* d0, ushort_t* d1, ushort_t* d2)
{
    const float* __restrict__ src = (blockIdx.y == 0) ? s0 : (blockIdx.y == 1) ? s1 : s2;
    ushort_t* __restrict__ dst = (blockIdx.y == 0) ? d0 : (blockIdx.y == 1) ? d1 : d2;
    size_t i = ((size_t)blockIdx.x * 256 + threadIdx.x) * 8;
    float4 a = *(const float4*)&src[i];
    float4 b = *(const float4*)&src[i + 4];
    uint4 o;
    o.x = pack2bf(a.x, a.y); o.y = pack2bf(a.z, a.w);
    o.z = pack2bf(b.x, b.y); o.w = pack2bf(b.z, b.w);
    *(uint4*)&dst[i] = o;
}

__global__ __launch_bounds__(256) void cvt_weights(
    const float* w0, const float* w1, const float* w2, const float* w3,
    const float* w4, const float* w5, const float* w6, const float* w7,
    ushort_t* __restrict__ out)
{
    const float* srcs[8] = {w0, w1, w2, w3, w4, w5, w6, w7};
    const float* __restrict__ src = srcs[blockIdx.y];
    ushort_t* __restrict__ dst = out + (size_t)blockIdx.y * E_DIM * E_DIM;
    size_t i = ((size_t)blockIdx.x * 256 + threadIdx.x) * 8;
    float4 a = *(const float4*)&src[i];
    float4 b = *(const float4*)&src[i + 4];
    uint4 o;
    o.x = pack2bf(a.x, a.y); o.y = pack2bf(a.z, a.w);
    o.z = pack2bf(b.x, b.y); o.w = pack2bf(b.z, b.w);
    *(uint4*)&dst[i] = o;
}

// ---------------------------------------------------------------------------
// Shared GEMM core: 128x128 tile, BK=32, global_load_lds staging.
// ---------------------------------------------------------------------------
template<bool OUT_BF16>
__device__ __forceinline__ void gemm_core(
    const ushort_t* __restrict__ x, const ushort_t* __restrict__ W,
    const float* __restrict__ bias, void* __restrict__ outv,
    int m0, int n0, int split, int kind, float scale, int T_)
{
    __shared__ __align__(16) ushort_t As[128 * 32];
    __shared__ __align__(16) ushort_t Bs[128 * 32];

    const int tid  = threadIdx.x;
    const int lane = tid & 63;
    const int wv   = tid >> 6;
    const int rw   = (wv >> 1) * 64;
    const int cw   = (wv & 1) * 64;
    const int am   = lane & 15;
    const int aq   = lane >> 4;

    const int grow = wv * 32 + (lane >> 2);
    const int gcol = (lane & 3) * 8;

    floatx4 acc[4][4];
    #pragma unroll
    for (int i = 0; i < 4; ++i)
        #pragma unroll
        for (int j = 0; j < 4; ++j)
            acc[i][j] = (floatx4){0.f, 0.f, 0.f, 0.f};

    for (int k0 = 0; k0 < E_DIM; k0 += 32) {
        load_lds16(&x[(size_t)(m0 + grow) * E_DIM + k0 + gcol],      &As[(wv * 32) * 32]);
        load_lds16(&x[(size_t)(m0 + grow + 16) * E_DIM + k0 + gcol], &As[(wv * 32 + 16) * 32]);
        load_lds16(&W[(size_t)(n0 + grow) * E_DIM + k0 + gcol],      &Bs[(wv * 32) * 32]);
        load_lds16(&W[(size_t)(n0 + grow + 16) * E_DIM + k0 + gcol], &Bs[(wv * 32 + 16) * 32]);
        __syncthreads();

        bf16x8 af[4], bfv[4];
        #pragma unroll
        for (int i = 0; i < 4; ++i)
            af[i] = *(const bf16x8*)&As[(rw + i * 16 + am) * 32 + aq * 8];
        #pragma unroll
        for (int j = 0; j < 4; ++j)
            bfv[j] = *(const bf16x8*)&Bs[(cw + j * 16 + am) * 32 + aq * 8];

        #pragma unroll
        for (int i = 0; i < 4; ++i)
            #pragma unroll
            for (int j = 0; j < 4; ++j)
                acc[i][j] = __builtin_amdgcn_mfma_f32_16x16x32_bf16(af[i], bfv[j], acc[i][j], 0, 0, 0);
        __syncthreads();
    }

    const int cq = lane >> 4;
    const int cm = lane & 15;
    #pragma unroll
    for (int j = 0; j < 4; ++j) {
        int n = n0 + cw + j * 16 + cm;
        float bv = bias[n];
        #pragma unroll
        for (int i = 0; i < 4; ++i) {
            int mbase = m0 + rw + i * 16 + cq * 4;
            #pragma unroll
            for (int r = 0; r < 4; ++r) {
                int m = mbase + r;
                int t = m % T_;
                if (((t < split) ? 0 : 1) != kind) continue;
                float val = (acc[i][j][r] + bv) * scale;
                if (OUT_BF16) ((ushort_t*)outv)[(size_t)m * E_DIM + n] = f2bf(val);
                else          ((float*)outv)[(size_t)m * E_DIM + n] = val;
            }
        }
    }
}

// Fused Q/K/V multiway GEMMs: blockIdx.z = op*2 + kind, op in {0,1,2}
__global__ __launch_bounds__(256) void gemm_qkv(
    const ushort_t* __restrict__ xq, const ushort_t* __restrict__ xk,
    const ushort_t* __restrict__ xv, const ushort_t* __restrict__ wall,
    const float* bq_t, const float* bq_i, const float* bk_t, const float* bk_i,
    const float* bv_t, const float* bv_i,
    ushort_t* oq, ushort_t* ok, ushort_t* ov,
    const int* __restrict__ split_ptr, int T_)
{
    const int split = *split_ptr;
    const int z = blockIdx.z;
    const int op = z >> 1;
    const int kind = z & 1;
    const int m0 = blockIdx.y * 128;
    const int n0 = blockIdx.x * 128;
    const int t0 = m0 % T_;

    if (kind == 0) { if (t0 >= split) return; }
    else           { if (t0 + 128 <= split) return; }

    const ushort_t* x = (op == 0) ? xq : (op == 1) ? xk : xv;
    ushort_t* outp    = (op == 0) ? oq : (op == 1) ? ok : ov;
    const ushort_t* W = wall + (size_t)z * E_DIM * E_DIM;
    const float* bias = (op == 0) ? (kind ? bq_i : bq_t)
                      : (op == 1) ? (kind ? bk_i : bk_t)
                                  : (kind ? bv_i : bv_t);
    float scale = (op == 0) ? 0.125f : 1.0f;

    gemm_core<true>(x, W, bias, outp, m0, n0, split, kind, scale, T_);
}

// Single multiway GEMM (final projection, fp32 out)
__global__ __launch_bounds__(256) void gemm_o(
    const ushort_t* __restrict__ x, const ushort_t* __restrict__ Wt,
    const float* bt, const ushort_t* __restrict__ Wi, const float* bi,
    float* __restrict__ outp, const int* __restrict__ split_ptr, int T_)
{
    const int split = *split_ptr;
    const int kind = blockIdx.z;
    const int m0 = blockIdx.y * 128;
    const int n0 = blockIdx.x * 128;
    const int t0 = m0 % T_;

    if (kind == 0) { if (t0 >= split) return; }
    else           { if (t0 + 128 <= split) return; }

    gemm_core<false>(x, kind ? Wi : Wt, kind ? bi : bt, outp, m0, n0, split, kind, 1.0f, T_);
}

// ---------------------------------------------------------------------------
// Flash attention, bf16 MFMA. Block = 128 Q-rows of one (b,h); 4 waves, each
// wave handles 2 Q-subtiles of 16 rows. K/V layouts identical to round 5.
// P buffer reused across subtiles (wave-private, in-order LDS pipe).
// ---------------------------------------------------------------------------
__global__ __launch_bounds__(256) void attn_mfma2(
    const ushort_t* __restrict__ q, const ushort_t* __restrict__ k,
    const ushort_t* __restrict__ v, const float* __restrict__ mask,
    ushort_t* __restrict__ outp, int T_)
{
    const int tid  = threadIdx.x;
    const int lane = tid & 63;
    const int wv   = tid >> 6;
    const int h    = blockIdx.y;
    const int b    = blockIdx.z;
    const int r0   = blockIdx.x * 128;

    __shared__ __align__(16) unsigned short Qs[2 * 128 * 40];   // plane stride 5120
    __shared__ __align__(16) unsigned short Ks[2 * 64 * 40];
    __shared__ __align__(16) unsigned short Vst[2 * 64 * 40];
    __shared__ __align__(16) unsigned short Ps[4 * 2 * 16 * 40];

    const int m    = lane & 15;
    const int kq   = lane >> 4;
    const int wrow = wv * 16;

    // ---- stage Q (128 rows x 64 cols) ----
    #pragma unroll
    for (int i = 0; i < 8; ++i) {
        int f   = tid + 256 * i;
        int row = f >> 4;
        int c4  = (f & 15) * 4;
        uint2 a2 = *(const uint2*)&q[((size_t)(b * T_ + r0 + row)) * E_DIM + h * HD + c4];
        int ad = (c4 >> 5) * 5120 + row * 40 + (c4 & 31);
        *(unsigned int*)&Qs[ad]     = a2.x;
        *(unsigned int*)&Qs[ad + 2] = a2.y;
    }
    __syncthreads();

    bf16x8 aq[2][2];
    #pragma unroll
    for (int qs = 0; qs < 2; ++qs)
        #pragma unroll
        for (int c = 0; c < 2; ++c)
            aq[qs][c] = *(const bf16x8*)&Qs[c * 5120 + (qs * 64 + wrow + m) * 40 + kq * 8];

    floatx4 oa[2][4];
    float mrun[2][4], lsum[2][4];
    #pragma unroll
    for (int qs = 0; qs < 2; ++qs)
        #pragma unroll
        for (int j = 0; j < 4; ++j) {
            oa[qs][j] = (floatx4){0.f, 0.f, 0.f, 0.f};
            mrun[qs][j] = -3.0e38f; lsum[qs][j] = 0.f;
        }

    const int vs0 = (tid >> 4) * 4;
    const int vd0 = (tid & 15) * 4;

    #pragma unroll 1
    for (int s0 = 0; s0 < T_; s0 += 64) {
        __syncthreads();

        // stage K tile
        #pragma unroll
        for (int i = 0; i < 4; ++i) {
            int f   = tid + 256 * i;
            int row = f >> 4;
            int c4  = (f & 15) * 4;
            uint2 a2 = *(const uint2*)&k[((size_t)(b * T_ + s0 + row)) * E_DIM + h * HD + c4];
            int ad = (c4 >> 5) * 2560 + row * 40 + (c4 & 31);
            *(unsigned int*)&Ks[ad]     = a2.x;
            *(unsigned int*)&Ks[ad + 2] = a2.y;
        }

        // stage V tile transposed
        {
            uint2 vvr[4];
            #pragma unroll
            for (int i = 0; i < 4; ++i)
                vvr[i] = *(const uint2*)&v[((size_t)(b * T_ + s0 + vs0 + i)) * E_DIM + h * HD + vd0];
            const ushort_t* vp = (const ushort_t*)vvr;
            int plane = (vs0 >> 5) * 2560;
            int sin   = vs0 & 31;
            #pragma unroll
            for (int t = 0; t < 4; ++t) {
                int d  = vd0 + t;
                int pr = d ^ ((d >> 4) & 3);
                uint2 w;
                w.x = (unsigned int)vp[0 * 4 + t] | ((unsigned int)vp[1 * 4 + t] << 16);
                w.y = (unsigned int)vp[2 * 4 + t] | ((unsigned int)vp[3 * 4 + t] << 16);
                *(uint2*)&Vst[plane + pr * 40 + sin] = w;
            }
        }

        __syncthreads();

        #pragma unroll
        for (int qs = 0; qs < 2; ++qs) {
            // mask prefetch for this q-subtile
            float mv[4][4];
            {
                const float* mbase = &mask[(size_t)(r0 + qs * 64 + wrow + kq * 4) * T_ + s0 + m];
                #pragma unroll
                for (int j = 0; j < 4; ++j)
                    #pragma unroll
                    for (int r = 0; r < 4; ++r)
                        mv[j][r] = mbase[r * T_ + j * 16];
            }

            // ---- QK^T ----
            floatx4 sa[4];
            #pragma unroll
            for (int j = 0; j < 4; ++j) sa[j] = (floatx4){0.f, 0.f, 0.f, 0.f};
            #pragma unroll
            for (int c = 0; c < 2; ++c) {
                #pragma unroll
                for (int j = 0; j < 4; ++j) {
                    bf16x8 bk = *(const bf16x8*)&Ks[c * 2560 + (j * 16 + m) * 40 + kq * 8];
                    sa[j] = __builtin_amdgcn_mfma_f32_16x16x32_bf16(aq[qs][c], bk, sa[j], 0, 0, 0);
                }
            }

            // ---- online softmax ----
            float mnew[4], alpha[4];
            #pragma unroll
            for (int r = 0; r < 4; ++r) {
                sa[0][r] += mv[0][r]; sa[1][r] += mv[1][r];
                sa[2][r] += mv[2][r]; sa[3][r] += mv[3][r];
                float mt = fmaxf(fmaxf(sa[0][r], sa[1][r]), fmaxf(sa[2][r], sa[3][r]));
                mt = fmaxf(mt, __shfl_xor(mt, 1));
                mt = fmaxf(mt, __shfl_xor(mt, 2));
                mt = fmaxf(mt, __shfl_xor(mt, 4));
                mt = fmaxf(mt, __shfl_xor(mt, 8));
                float mn = fmaxf(mrun[qs][r], mt);
                alpha[r] = __expf(mrun[qs][r] - mn);
                mnew[r] = mn;
                mrun[qs][r] = mn;
            }
            #pragma unroll
            for (int j = 0; j < 4; ++j)
                #pragma unroll
                for (int r = 0; r < 4; ++r)
                    oa[qs][j][r] *= alpha[r];

            float rs[4] = {0.f, 0.f, 0.f, 0.f};
            #pragma unroll
            for (int j = 0; j < 4; ++j) {
                int gl = ((((j & 1) << 1) | (m >> 3)) ^ kq) & 3;
                int pbase = wv * 1280 + (j >> 1) * 640 + (kq * 4) * 40 + gl * 8 + (m & 7);
                #pragma unroll
                for (int r = 0; r < 4; ++r) {
                    float p = __expf(sa[j][r] - mnew[r]);
                    rs[r] += p;
                    Ps[pbase + r * 40] = f2bf(p);
                }
            }
            #pragma unroll
            for (int r = 0; r < 4; ++r) {
                float s = rs[r];
                s += __shfl_xor(s, 1); s += __shfl_xor(s, 2);
                s += __shfl_xor(s, 4); s += __shfl_xor(s, 8);
                lsum[qs][r] = lsum[qs][r] * alpha[r] + s;
            }

            // ---- PV ----
            #pragma unroll
            for (int c = 0; c < 2; ++c) {
                bf16x8 ap = *(const bf16x8*)&Ps[wv * 1280 + c * 640 + m * 40 + ((kq ^ (m >> 2)) & 3) * 8];
                #pragma unroll
                for (int j = 0; j < 4; ++j) {
                    int pr = 16 * j + (m ^ j);
                    bf16x8 bv = *(const bf16x8*)&Vst[c * 2560 + pr * 40 + kq * 8];
                    oa[qs][j] = __builtin_amdgcn_mfma_f32_16x16x32_bf16(ap, bv, oa[qs][j], 0, 0, 0);
                }
            }
        }
    }

    // ---- epilogue ----
    #pragma unroll
    for (int qs = 0; qs < 2; ++qs)
        #pragma unroll
        for (int r = 0; r < 4; ++r) {
            float inv = 1.0f / lsum[qs][r];
            size_t orow = ((size_t)(b * T_ + r0 + qs * 64 + wrow + kq * 4 + r)) * E_DIM + h * HD;
            #pragma unroll
            for (int j = 0; j < 4; ++j)
                outp[orow + j * 16 + m] = f2bf(oa[qs][j][r] * inv);
        }
}

// ---------------------------------------------------------------------------
// Multiway LayerNorm, bf16 in / bf16 out, fp32 stats. One block per row.
// ---------------------------------------------------------------------------
__global__ __launch_bounds__(256) void mw_ln_bf16(
    const ushort_t* __restrict__ x,
    const float* __restrict__ gt, const float* __restrict__ bt,
    const float* __restrict__ gi, const float* __restrict__ bi,
    ushort_t* __restrict__ out,
    const int* __restrict__ split_ptr, int T_)
{
    const int split = *split_ptr;
    const int row = blockIdx.x;
    const int t = row % T_;
    const float* __restrict__ g  = (t < split) ? gt : gi;
    const float* __restrict__ bb = (t < split) ? bt : bi;

    const int tid = threadIdx.x;
    const int lane = tid & 63;
    const int wid = tid >> 6;

    __shared__ float red[8];

    uint2 xv = *(const uint2*)&x[(size_t)row * E_DIM + tid * 4];
    float f0 = bf2f(xv.x & 0xffffu), f1 = bf2f(xv.x >> 16);
    float f2 = bf2f(xv.y & 0xffffu), f3 = bf2f(xv.y >> 16);
    float s = f0 + f1 + f2 + f3;
    #pragma unroll
    for (int off = 1; off < 64; off <<= 1) s += __shfl_xor(s, off, 64);
    if (lane == 0) red[wid] = s;
    __syncthreads();
    float mu = (red[0] + red[1] + red[2] + red[3]) * (1.0f / E_DIM);

    float d0 = f0 - mu, d1 = f1 - mu, d2 = f2 - mu, d3 = f3 - mu;
    float s2 = d0*d0 + d1*d1 + d2*d2 + d3*d3;
    #pragma unroll
    for (int off = 1; off < 64; off <<= 1) s2 += __shfl_xor(s2, off, 64);
    if (lane == 0) red[4 + wid] = s2;
    __syncthreads();
    float var = (red[4] + red[5] + red[6] + red[7]) * (1.0f / E_DIM);
    float rstd = rsqrtf(var + 1e-5f);

    float4 gv = *(const float4*)&g[tid * 4];
    float4 bv = *(const float4*)&bb[tid * 4];
    uint2 ov;
    ov.x = pack2bf(d0 * rstd * gv.x + bv.x, d1 * rstd * gv.y + bv.y);
    ov.y = pack2bf(d2 * rstd * gv.z + bv.z, d3 * rstd * gv.w + bv.w);
    *(uint2*)&out[(size_t)row * E_DIM + tid * 4] = ov;
}

// ---------------------------------------------------------------------------
extern "C" void kernel_launch(void* const* d_in, const int* in_sizes, int n_in,
                              void* d_out, int out_size, void* d_ws, size_t ws_size,
                              hipStream_t stream) {
    const float* query = (const float*)d_in[0];
    const float* key   = (const float*)d_in[1];
    const float* value = (const float*)d_in[2];
    const float* mask  = (const float*)d_in[3];
    const float* Wq_t = (const float*)d_in[4];  const float* bq_t = (const float*)d_in[5];
    const float* Wq_i = (const float*)d_in[6];  const float* bq_i = (const float*)d_in[7];
    const float* Wk_t = (const float*)d_in[8];  const float* bk_t = (const float*)d_in[9];
    const float* Wk_i = (const float*)d_in[10]; const float* bk_i = (const float*)d_in[11];
    const float* Wv_t = (const float*)d_in[12]; const float* bv_t = (const float*)d_in[13];
    const float* Wv_i = (const float*)d_in[14]; const float* bv_i = (const float*)d_in[15];
    const float* Wo_t = (const float*)d_in[16]; const float* bo_t = (const float*)d_in[17];
    const float* Wo_i = (const float*)d_in[18]; const float* bo_i = (const float*)d_in[19];
    const float* ln_g_t = (const float*)d_in[20]; const float* ln_b_t = (const float*)d_in[21];
    const float* ln_g_i = (const float*)d_in[22]; const float* ln_b_i = (const float*)d_in[23];
    const int* split = (const int*)d_in[24];

    float* out = (float*)d_out;

    const int BT = in_sizes[0] / E_DIM;   // B*T = 8192
    const int T_ = 1024;
    const int B  = BT / T_;

    ushort_t* ws = (ushort_t*)d_ws;
    const size_t nx = (size_t)BT * E_DIM;        // 8M elements
    const size_t nw = (size_t)E_DIM * E_DIM;     // 1M elements
    ushort_t* xq_bf = ws;                // converted query; later LN output
    ushort_t* xk_bf = ws + nx;
    ushort_t* xv_bf = ws + 2 * nx;
    ushort_t* k_bf  = ws + 3 * nx;
    ushort_t* v_bf  = ws + 4 * nx;
    ushort_t* w_bf  = ws + 5 * nx;       // 8 weights = 8*nw = nx elements
    ushort_t* q_bf  = (ushort_t*)d_out;  // bf16 scratch inside d_out (overwritten by gemm_o)

    dim3 blk(256);
    const int cvt_blocks = (int)(nx / 2048);
    const int wcvt_blocks = (int)(nw / 2048);

    cvt_weights<<<dim3(wcvt_blocks, 8), blk, 0, stream>>>(
        Wq_t, Wq_i, Wk_t, Wk_i, Wv_t, Wv_i, Wo_t, Wo_i, w_bf);
    cvt_inputs<<<dim3(cvt_blocks, 3), blk, 0, stream>>>(
        query, key, value, xq_bf, xk_bf, xv_bf);

    gemm_qkv<<<dim3(E_DIM / 128, BT / 128, 6), blk, 0, stream>>>(
        xq_bf, xk_bf, xv_bf, w_bf,
        bq_t, bq_i, bk_t, bk_i, bv_t, bv_i,
        q_bf, k_bf, v_bf, split, T_);

    attn_mfma2<<<dim3(T_ / 128, HEADS, B), blk, 0, stream>>>(
        q_bf, k_bf, v_bf, mask, q_bf, T_);

    mw_ln_bf16<<<dim3(BT), blk, 0, stream>>>(
        q_bf, ln_g_t, ln_b_t, ln_g_i, ln_b_i, xq_bf, split, T_);

    gemm_o<<<dim3(E_DIM / 128, BT / 128, 2), blk, 0, stream>>>(
        xq_bf, w_bf + 6 * nw, bo_t, w_bf + 7 * nw, bo_i, out, split, T_);
}